// Round 1
// baseline (1077.210 us; speedup 1.0000x reference)
//
#include <hip/hip_runtime.h>
#include <cstdint>
#include <cstddef>

#define H 768
#define NHEAD 12
#define DH 64
#define FFD 3072
#define BATCH 8
#define SEQ 1024
#define NTOK (BATCH*SEQ)   // 8192

typedef __bf16 bf16x8 __attribute__((ext_vector_type(8)));
typedef float  floatx4 __attribute__((ext_vector_type(4)));

#define MFMA_BF16(a,b,c) __builtin_amdgcn_mfma_f32_16x16x32_bf16((a),(b),(c),0,0,0)

// ---------------------------------------------------------------- LayerNorm
// one wave per row of 768 fp32; output bf16
__global__ __launch_bounds__(256) void ln_kernel(const float* __restrict__ x,
                                                 const float* __restrict__ g,
                                                 const float* __restrict__ be,
                                                 __bf16* __restrict__ out) {
    int row  = blockIdx.x * 4 + (threadIdx.x >> 6);
    int lane = threadIdx.x & 63;
    const float* xr = x + (size_t)row * H;
    float v[12];
    float s = 0.f;
#pragma unroll
    for (int i = 0; i < 12; i++) { v[i] = xr[lane + i * 64]; s += v[i]; }
#pragma unroll
    for (int m = 32; m >= 1; m >>= 1) s += __shfl_xor(s, m, 64);
    float mu = s * (1.0f / H);
    float q = 0.f;
#pragma unroll
    for (int i = 0; i < 12; i++) { float d = v[i] - mu; q += d * d; }
#pragma unroll
    for (int m = 32; m >= 1; m >>= 1) q += __shfl_xor(q, m, 64);
    float rstd = rsqrtf(q * (1.0f / H) + 1e-6f);
    __bf16* orow = out + (size_t)row * H;
#pragma unroll
    for (int i = 0; i < 12; i++) {
        int c = lane + i * 64;
        orow[c] = (__bf16)((v[i] - mu) * rstd * g[c] + be[c]);
    }
}

// ------------------------------------------------- weight fp32(K,N) -> bf16 T(N,K)
__global__ __launch_bounds__(256) void wtrans_kernel(const float* __restrict__ W,
                                                     __bf16* __restrict__ T,
                                                     int K, int Nn) {
    __shared__ float tile[32][33];
    int tx = threadIdx.x & 31;
    int ty = threadIdx.x >> 5;            // 0..7
    int n0 = blockIdx.x * 32, k0 = blockIdx.y * 32;
#pragma unroll
    for (int i = 0; i < 32; i += 8)
        tile[ty + i][tx] = W[(size_t)(k0 + ty + i) * Nn + n0 + tx];
    __syncthreads();
#pragma unroll
    for (int i = 0; i < 32; i += 8)
        T[(size_t)(n0 + ty + i) * K + k0 + tx] = (__bf16)tile[tx][ty + i];
}

// ------------------------------------------------- v (8192,768) -> vT (b,h,64,1024)
__global__ __launch_bounds__(256) void vtrans_kernel(const __bf16* __restrict__ v,
                                                     __bf16* __restrict__ vT) {
    __shared__ __bf16 tile[64][65];
    int b = blockIdx.z, h = blockIdx.y, n0 = blockIdx.x * 64;
    int tx = threadIdx.x, ty = threadIdx.y;
#pragma unroll
    for (int r = ty; r < 64; r += 4)
        tile[r][tx] = v[((size_t)b * SEQ + n0 + r) * H + h * DH + tx];
    __syncthreads();
#pragma unroll
    for (int c = ty; c < 64; c += 4)
        vT[(((size_t)b * NHEAD + h) * DH + c) * SEQ + n0 + tx] = tile[tx][c];
}

// ---------------------------------------------------------------- GEMM
// C(M,Nn) = A(M,K)bf16 @ Bt(Nn,K)bf16^T + bias ; optional erf-GELU, fp32 residual
// 128x128 tile, BK=32, 4 waves in 2x2, each wave 64x64 = 4x4 MFMA 16x16x32
template<bool GELU, bool HAS_RES, bool OUT_BF16>
__global__ __launch_bounds__(256) void gemm_kernel(const __bf16* __restrict__ A,
                                                   const __bf16* __restrict__ Bt,
                                                   const float* __restrict__ bias,
                                                   const float* __restrict__ res,
                                                   __bf16* __restrict__ obf,
                                                   float* __restrict__ ofp,
                                                   int Nn, int K) {
    __shared__ __bf16 As[128 * 32];
    __shared__ __bf16 Bs[128 * 32];
    int tid = threadIdx.x;
    int wave = tid >> 6, lane = tid & 63;
    int wr = wave >> 1, wc = wave & 1;
    int l15 = lane & 15, quad = lane >> 4;

    floatx4 acc[4][4];
    floatx4 zero = {0.f, 0.f, 0.f, 0.f};
#pragma unroll
    for (int i = 0; i < 4; i++)
#pragma unroll
        for (int j = 0; j < 4; j++) acc[i][j] = zero;

    int srow = tid >> 1;          // 0..127
    int scol = (tid & 1) * 16;    // 0 / 16
    const __bf16* Ag = A + (size_t)(blockIdx.y * 128 + srow) * K + scol;
    const __bf16* Bg = Bt + (size_t)(blockIdx.x * 128 + srow) * K + scol;
    __bf16* AsW = &As[srow * 32 + scol];
    __bf16* BsW = &Bs[srow * 32 + scol];

    for (int k0 = 0; k0 < K; k0 += 32) {
        *(bf16x8*)(AsW)     = *(const bf16x8*)(Ag + k0);
        *(bf16x8*)(AsW + 8) = *(const bf16x8*)(Ag + k0 + 8);
        *(bf16x8*)(BsW)     = *(const bf16x8*)(Bg + k0);
        *(bf16x8*)(BsW + 8) = *(const bf16x8*)(Bg + k0 + 8);
        __syncthreads();
        bf16x8 af[4], bfv[4];
#pragma unroll
        for (int i = 0; i < 4; i++)
            af[i] = *(const bf16x8*)&As[(wr * 64 + i * 16 + l15) * 32 + quad * 8];
#pragma unroll
        for (int j = 0; j < 4; j++)
            bfv[j] = *(const bf16x8*)&Bs[(wc * 64 + j * 16 + l15) * 32 + quad * 8];
#pragma unroll
        for (int i = 0; i < 4; i++)
#pragma unroll
            for (int j = 0; j < 4; j++)
                acc[i][j] = MFMA_BF16(af[i], bfv[j], acc[i][j]);
        __syncthreads();
    }

#pragma unroll
    for (int i = 0; i < 4; i++) {
        int row = blockIdx.y * 128 + wr * 64 + i * 16 + quad * 4;
#pragma unroll
        for (int j = 0; j < 4; j++) {
            int col = blockIdx.x * 128 + wc * 64 + j * 16 + l15;
            float bsv = bias[col];
#pragma unroll
            for (int r = 0; r < 4; r++) {
                float vv = acc[i][j][r] + bsv;
                if (GELU) vv = 0.5f * vv * (1.0f + erff(vv * 0.70710678118654752f));
                if (HAS_RES) vv += res[(size_t)(row + r) * Nn + col];
                if (OUT_BF16) obf[(size_t)(row + r) * Nn + col] = (__bf16)vv;
                else          ofp[(size_t)(row + r) * Nn + col] = vv;
            }
        }
    }
}

// ---------------------------------------------------------------- Attention
// per block: 16 query rows of one (b,h): S=q@k^T/sqrt(H) -> softmax -> W out (fp32)
// -> ctx = W@v via MFMA. S kept in 64KB LDS with XOR swizzle on col bits 2..4.
__device__ __forceinline__ int sidx(int row, int col) {
    return row * 1024 + (col ^ ((row & 7) << 2));
}

__global__ __launch_bounds__(256) void attn_kernel(const __bf16* __restrict__ q,
                                                   const __bf16* __restrict__ k,
                                                   const __bf16* __restrict__ vT,
                                                   float* __restrict__ Wout,
                                                   __bf16* __restrict__ ctx) {
    __shared__ float S[16 * 1024];   // 65536 B
    int tid = threadIdx.x;
    int wave = tid >> 6, lane = tid & 63, l15 = lane & 15, quad = lane >> 4;
    int rt = blockIdx.x, h = blockIdx.y, b = blockIdx.z;
    const size_t qkbase = ((size_t)b * SEQ) * H + h * DH;
    const float scale = 0.03608439182435161f;   // 1/sqrt(768)

    // q fragments (16 rows x 64 k) held in regs, shared by all column tiles
    const __bf16* qrow = q + qkbase + (size_t)(rt * 16 + l15) * H;
    bf16x8 qf0 = *(const bf16x8*)(qrow + quad * 8);
    bf16x8 qf1 = *(const bf16x8*)(qrow + 32 + quad * 8);

    for (int ct = wave; ct < 64; ct += 4) {
        const __bf16* krow = k + qkbase + (size_t)(ct * 16 + l15) * H;
        bf16x8 kf0 = *(const bf16x8*)(krow + quad * 8);
        bf16x8 kf1 = *(const bf16x8*)(krow + 32 + quad * 8);
        floatx4 acc = {0.f, 0.f, 0.f, 0.f};
        acc = MFMA_BF16(qf0, kf0, acc);
        acc = MFMA_BF16(qf1, kf1, acc);
#pragma unroll
        for (int r = 0; r < 4; r++)
            S[sidx(quad * 4 + r, ct * 16 + l15)] = acc[r] * scale;
    }
    __syncthreads();

    // softmax: 16 lanes per row
    {
        int g = tid >> 4, lg = tid & 15;
        float mx = -1e30f;
        for (int c = lg; c < 1024; c += 16) mx = fmaxf(mx, S[sidx(g, c)]);
        mx = fmaxf(mx, __shfl_xor(mx, 1, 64));
        mx = fmaxf(mx, __shfl_xor(mx, 2, 64));
        mx = fmaxf(mx, __shfl_xor(mx, 4, 64));
        mx = fmaxf(mx, __shfl_xor(mx, 8, 64));
        float sum = 0.f;
        for (int c = lg; c < 1024; c += 16) {
            float e = __expf(S[sidx(g, c)] - mx);
            S[sidx(g, c)] = e;
            sum += e;
        }
        sum += __shfl_xor(sum, 1, 64);
        sum += __shfl_xor(sum, 2, 64);
        sum += __shfl_xor(sum, 4, 64);
        sum += __shfl_xor(sum, 8, 64);
        float inv = 1.0f / sum;
        for (int c = lg; c < 1024; c += 16) S[sidx(g, c)] *= inv;
    }
    __syncthreads();

    // write weights (fp32, coalesced float4)
    size_t wbase = (((size_t)b * NHEAD + h) * SEQ + rt * 16) * SEQ;
#pragma unroll
    for (int it = 0; it < 16; it++) {
        int col = tid * 4;                 // 0..1020
        int row = it;
        float4 vv = *(const float4*)&S[sidx(row, col)];
        *(float4*)&Wout[wbase + (size_t)row * SEQ + col] = vv;
    }

    // PV: ctx(16x64) = W(16x1024) @ v(1024x64); wave owns 16 d-cols
    floatx4 acc = {0.f, 0.f, 0.f, 0.f};
    const __bf16* vbase = vT + (((size_t)b * NHEAD + h) * DH + wave * 16 + l15) * SEQ;
    for (int ks = 0; ks < 32; ks++) {
        int cb = ks * 32 + quad * 8;
        float4 s0 = *(const float4*)&S[sidx(l15, cb)];
        float4 s1 = *(const float4*)&S[sidx(l15, cb + 4)];
        bf16x8 af;
        af[0] = (__bf16)s0.x; af[1] = (__bf16)s0.y; af[2] = (__bf16)s0.z; af[3] = (__bf16)s0.w;
        af[4] = (__bf16)s1.x; af[5] = (__bf16)s1.y; af[6] = (__bf16)s1.z; af[7] = (__bf16)s1.w;
        bf16x8 bv = *(const bf16x8*)(vbase + ks * 32 + quad * 8);
        acc = MFMA_BF16(af, bv, acc);
    }
#pragma unroll
    for (int r = 0; r < 4; r++)
        ctx[((size_t)b * SEQ + rt * 16 + quad * 4 + r) * H + h * DH + wave * 16 + l15] =
            (__bf16)acc[r];
}

// ---------------------------------------------------------------- launch
extern "C" void kernel_launch(void* const* d_in, const int* in_sizes, int n_in,
                              void* d_out, int out_size, void* d_ws, size_t ws_size,
                              hipStream_t stream) {
    const float* x   = (const float*)d_in[0];
    const float* wq  = (const float*)d_in[1];
    const float* bq  = (const float*)d_in[2];
    const float* wk  = (const float*)d_in[3];
    const float* bk  = (const float*)d_in[4];
    const float* wv  = (const float*)d_in[5];
    const float* bv  = (const float*)d_in[6];
    const float* wo  = (const float*)d_in[7];
    const float* bo  = (const float*)d_in[8];
    const float* w1  = (const float*)d_in[9];
    const float* b1  = (const float*)d_in[10];
    const float* w2  = (const float*)d_in[11];
    const float* b2  = (const float*)d_in[12];
    const float* g1  = (const float*)d_in[13];
    const float* be1 = (const float*)d_in[14];
    const float* g2  = (const float*)d_in[15];
    const float* be2 = (const float*)d_in[16];

    char* ws = (char*)d_ws;
    const size_t SZB = (size_t)NTOK * H * 2;           // 12582912
    __bf16* x1b  = (__bf16*)(ws);
    __bf16* qb   = (__bf16*)(ws + SZB);
    __bf16* kb   = (__bf16*)(ws + 2 * SZB);
    __bf16* vb   = (__bf16*)(ws + 3 * SZB);
    __bf16* vTb  = (__bf16*)(ws + 4 * SZB);
    __bf16* ctxb = (__bf16*)(ws + 5 * SZB);
    __bf16* x2b  = (__bf16*)(ws + 6 * SZB);
    __bf16* hb   = (__bf16*)(ws + 7 * SZB);            // 8192*3072*2
    size_t off = 7 * SZB + (size_t)NTOK * FFD * 2;
    float* xattn = (float*)(ws + off); off += (size_t)NTOK * H * 4;
    __bf16* wqT = (__bf16*)(ws + off); off += (size_t)H * H * 2;
    __bf16* wkT = (__bf16*)(ws + off); off += (size_t)H * H * 2;
    __bf16* wvT = (__bf16*)(ws + off); off += (size_t)H * H * 2;
    __bf16* woT = (__bf16*)(ws + off); off += (size_t)H * H * 2;
    __bf16* w1T = (__bf16*)(ws + off); off += (size_t)H * FFD * 2;
    __bf16* w2T = (__bf16*)(ws + off); off += (size_t)FFD * H * 2;

    float* outx = (float*)d_out;
    float* outw = (float*)d_out + (size_t)NTOK * H;

    // weights -> bf16, transposed to (N,K)
    wtrans_kernel<<<dim3(24, 24), 256, 0, stream>>>(wq, wqT, H, H);
    wtrans_kernel<<<dim3(24, 24), 256, 0, stream>>>(wk, wkT, H, H);
    wtrans_kernel<<<dim3(24, 24), 256, 0, stream>>>(wv, wvT, H, H);
    wtrans_kernel<<<dim3(24, 24), 256, 0, stream>>>(wo, woT, H, H);
    wtrans_kernel<<<dim3(96, 24), 256, 0, stream>>>(w1, w1T, H, FFD);
    wtrans_kernel<<<dim3(24, 96), 256, 0, stream>>>(w2, w2T, FFD, H);

    // LN1
    ln_kernel<<<NTOK / 4, 256, 0, stream>>>(x, g1, be1, x1b);

    // QKV projections
    gemm_kernel<false, false, true><<<dim3(H / 128, NTOK / 128), 256, 0, stream>>>(
        x1b, wqT, bq, nullptr, qb, nullptr, H, H);
    gemm_kernel<false, false, true><<<dim3(H / 128, NTOK / 128), 256, 0, stream>>>(
        x1b, wkT, bk, nullptr, kb, nullptr, H, H);
    gemm_kernel<false, false, true><<<dim3(H / 128, NTOK / 128), 256, 0, stream>>>(
        x1b, wvT, bv, nullptr, vb, nullptr, H, H);

    // v -> vT (b,h,d,n)
    vtrans_kernel<<<dim3(16, NHEAD, BATCH), dim3(64, 4), 0, stream>>>(vb, vTb);

    // attention (writes softmax weights to d_out and ctx to ws)
    attn_kernel<<<dim3(64, NHEAD, BATCH), 256, 0, stream>>>(qb, kb, vTb, outw, ctxb);

    // out projection + residual(x) -> xattn fp32
    gemm_kernel<false, true, false><<<dim3(H / 128, NTOK / 128), 256, 0, stream>>>(
        ctxb, woT, bo, x, nullptr, xattn, H, H);

    // LN2
    ln_kernel<<<NTOK / 4, 256, 0, stream>>>(xattn, g2, be2, x2b);

    // FFN1 + exact GELU
    gemm_kernel<true, false, true><<<dim3(FFD / 128, NTOK / 128), 256, 0, stream>>>(
        x2b, w1T, b1, nullptr, hb, nullptr, FFD, H);

    // FFN2 + residual(xattn) -> d_out[0:6291456]
    gemm_kernel<false, true, false><<<dim3(H / 128, NTOK / 128), 256, 0, stream>>>(
        hb, w2T, b2, xattn, nullptr, outx, H, FFD);
}